// Round 6
// baseline (576.576 us; speedup 1.0000x reference)
//
#include <hip/hip_runtime.h>
#include <math.h>

#define NNODES 50000
#define NEDGES 800000
#define AVGDLOG 2.833f
#define EPSF 1e-5f
#define CHUNK 448
#define MAXS 576
#define NCHUNK (NEDGES / CHUNK + 1)

typedef __attribute__((ext_vector_type(8))) short short8;
typedef __attribute__((ext_vector_type(4))) float f32x4;

__device__ __forceinline__ unsigned f2bf(float x) {
    unsigned u = __float_as_uint(x);
    return (u + 0x7FFFu + ((u >> 16) & 1u)) >> 16;
}
__device__ __forceinline__ float bf2f(unsigned lo16) {
    return __uint_as_float(lo16 << 16);
}

// ---------------- CSR ----------------
__global__ void k_zero(unsigned* __restrict__ deg) {
    int i = blockIdx.x * 256 + threadIdx.x;
    if (i < NNODES) deg[i] = 0u;
}
__global__ void k_count(const int* __restrict__ dst, unsigned* __restrict__ deg) {
    int i = blockIdx.x * 256 + threadIdx.x;
    if (i < NEDGES) atomicAdd(&deg[dst[i]], 1u);
}
__global__ __launch_bounds__(1024) void k_scan(const unsigned* __restrict__ deg,
                                               int* __restrict__ base, int* __restrict__ cursor) {
    __shared__ int ps[1024];
    const int t = threadIdx.x;
    const int lo = t * 52;
    int s = 0;
    if (lo + 52 <= NNODES) {
        const int4* dp = (const int4*)(deg + lo);
#pragma unroll
        for (int i = 0; i < 13; ++i) { int4 v = dp[i]; s += v.x + v.y + v.z + v.w; }
    } else {
        for (int i = lo; i < NNODES; ++i) s += (int)deg[i];
    }
    ps[t] = s;
    __syncthreads();
    for (int off = 1; off < 1024; off <<= 1) {
        int v = (t >= off) ? ps[t - off] : 0;
        __syncthreads();
        ps[t] += v;
        __syncthreads();
    }
    int run = (t > 0) ? ps[t - 1] : 0;
    if (lo + 52 <= NNODES) {
        const int4* dp = (const int4*)(deg + lo);
        int4* bp = (int4*)(base + lo);
        int4* cp = (int4*)(cursor + lo);
#pragma unroll
        for (int i = 0; i < 13; ++i) {
            int4 v = dp[i]; int4 b;
            b.x = run; run += v.x; b.y = run; run += v.y;
            b.z = run; run += v.z; b.w = run; run += v.w;
            bp[i] = b; cp[i] = b;
        }
    } else {
        for (int i = lo; i < NNODES; ++i) { base[i] = run; cursor[i] = run; run += (int)deg[i]; }
    }
    if (t == 1023) base[NNODES] = run;
}
__global__ void k_scatter(const int* __restrict__ dst, const int* __restrict__ src,
                          int* __restrict__ cursor, int* __restrict__ sorted,
                          int* __restrict__ ssrc) {
    int i = blockIdx.x * 256 + threadIdx.x;
    if (i < NEDGES) {
        int d = dst[i];
        int slot = atomicAdd(&cursor[d], 1);
        sorted[slot] = i;
        ssrc[slot] = src[i];
    }
}

// ---------------- weight prep ----------------
__global__ void k_convW(const float* __restrict__ Wpre, const float* __restrict__ Wpost,
                        unsigned short* __restrict__ W3t, unsigned short* __restrict__ W12t,
                        unsigned short* __restrict__ Bhat) {
    int i = blockIdx.x * 256 + threadIdx.x;
    if (i < 128 * 128) {
        int n = i & 127, k = i >> 7;
        W3t[n * 128 + k] = (unsigned short)f2bf(Wpre[(256 + k) * 128 + n]);
    }
    if (i < 256 * 128) {
        int n = i >> 7, k = i & 127;
        float v = (n < 128) ? Wpre[k * 128 + n] : Wpre[(128 + k) * 128 + (n - 128)];
        W12t[n * 128 + k] = (unsigned short)f2bf(v);
    }
    if (i < 640 * 384) {
        int kc = i / (384 * 32);
        int rem = i % (384 * 32);
        int n = rem >> 5, kk = rem & 31;
        int k = kc * 32 + kk, c = n & 127, g = n >> 7;
        float v;
        if (g == 0) v = Wpost[k * 128 + c];
        else if (g == 1) v = (k < 128) ? 0.f : Wpost[(512 + k) * 128 + c];
        else v = (k < 128) ? 0.f : Wpost[(1024 + k) * 128 + c];
        Bhat[i] = (unsigned short)f2bf(v);
    }
}

// ---------------- P12 = h @ [W1|W2] (MFMA); also emits bf16(h) into Abuf[:,0:128] ----------------
__global__ __launch_bounds__(256) void k_p12(const float* __restrict__ h,
                                             const unsigned short* __restrict__ W12t,
                                             unsigned short* __restrict__ P1,
                                             unsigned short* __restrict__ P2,
                                             unsigned short* __restrict__ Abuf) {
    __shared__ __align__(16) unsigned short As[64 * 128];
    __shared__ __align__(16) unsigned short Bs[256 * 128];
    const int t = threadIdx.x;
    const size_t row0 = (size_t)blockIdx.x * 64;
#pragma unroll
    for (int j = 0; j < 16; ++j) {
        int idx = t + 256 * j;
        int n = idx >> 4, q = idx & 15;
        uint4 wv = *(const uint4*)(W12t + n * 128 + q * 8);
        *(uint4*)((char*)Bs + n * 256 + ((q * 16) ^ ((n & 7) << 4))) = wv;
    }
#pragma unroll
    for (int j = 0; j < 8; ++j) {
        int idx = t + 256 * j;
        int r = idx >> 5, q = idx & 31;
        size_t row = row0 + r;
        uint2 p = {0u, 0u};
        if (row < NNODES) {
            float4 z = ((const float4*)h)[row * 32 + q];
            p.x = f2bf(z.x) | (f2bf(z.y) << 16);
            p.y = f2bf(z.z) | (f2bf(z.w) << 16);
            *(uint2*)(Abuf + row * 640 + q * 4) = p;
        }
        *(uint2*)((char*)As + r * 256 + ((q * 8) ^ ((r & 7) << 4))) = p;
    }
    __syncthreads();
    const int w = t >> 6, lane = t & 63, lrow = lane & 15, lkb = lane >> 4;
    f32x4 acc[16];
#pragma unroll
    for (int i = 0; i < 16; ++i) acc[i] = (f32x4){0.f, 0.f, 0.f, 0.f};
    const char* Abase = (const char*)As + (w * 16 + lrow) * 256;
    const unsigned aswz = (unsigned)(((w * 16 + lrow) & 7) << 4);
#pragma unroll
    for (int kk = 0; kk < 4; ++kk) {
        int kbyte = (kk * 32 + lkb * 8) * 2;
        short8 af = *(const short8*)(Abase + (kbyte ^ aswz));
#pragma unroll
        for (int nt = 0; nt < 16; ++nt) {
            int n = nt * 16 + lrow;
            short8 bf = *(const short8*)((const char*)Bs + n * 256 + (kbyte ^ ((n & 7) << 4)));
            acc[nt] = __builtin_amdgcn_mfma_f32_16x16x32_bf16(af, bf, acc[nt], 0, 0, 0);
        }
    }
#pragma unroll
    for (int half = 0; half < 2; ++half) {
        __syncthreads();
#pragma unroll
        for (int nt = 0; nt < 8; ++nt) {
            int c = nt * 16 + lrow;
#pragma unroll
            for (int i = 0; i < 4; ++i) {
                int lr = w * 16 + lkb * 4 + i;
                *(unsigned short*)((char*)As + lr * 256 + ((c * 2) ^ ((lr & 7) << 4))) =
                    (unsigned short)f2bf(acc[half * 8 + nt][i]);
            }
        }
        __syncthreads();
        unsigned short* dstP = half ? P2 : P1;
#pragma unroll
        for (int j = 0; j < 4; ++j) {
            int idx = t + 256 * j;
            int r = idx >> 4, q = idx & 15;
            size_t row = row0 + r;
            if (row < NNODES) {
                uint4 v = *(const uint4*)((const char*)As + r * 256 + ((q * 16) ^ ((r & 7) << 4)));
                *(uint4*)(dstP + row * 128 + q * 8) = v;
            }
        }
    }
}

// ---------------- fused: per-chunk edge GEMM + segmented stats reduce ----------------
// Block c owns nodes n with basep[n] in [c*CHUNK, (c+1)*CHUNK) -> contiguous slots, no straddlers.
// g = e@W3 + bpre + P1[src]; stats(g) per node; P2[dst] folded in at flush (mean/max/min += c, std unchanged).
__global__ __launch_bounds__(256) void k_fused(const float* __restrict__ e,
                                               const int* __restrict__ sorted,
                                               const int* __restrict__ ssrc_g,
                                               const int* __restrict__ basep,
                                               const unsigned short* __restrict__ W3t,
                                               const float* __restrict__ bpre,
                                               const unsigned short* __restrict__ P1,
                                               const unsigned short* __restrict__ P2,
                                               unsigned short* __restrict__ Abuf) {
    __shared__ __align__(16) unsigned short Bs[128 * 128];
    __shared__ __align__(16) unsigned short As[64 * 128];
    __shared__ __align__(16) unsigned short P1s[64 * 128];
    __shared__ int seid[MAXS];
    __shared__ unsigned short ssr[MAXS];
    __shared__ unsigned short snode[MAXS];
    __shared__ int zlist[32];
    __shared__ int zcnt;

    const int t = threadIdx.x;
    const int cblk = blockIdx.x;
    if (t == 0) zcnt = 0;

    // binary search: firstNode = first n with basep[n] >= cblk*CHUNK; endNode likewise for +CHUNK
    const int tg1 = cblk * CHUNK, tg2 = tg1 + CHUNK;
    int lo = 0, hi = NNODES;
    while (lo < hi) { int mid = (lo + hi) >> 1; if (basep[mid] >= tg1) hi = mid; else lo = mid + 1; }
    const int firstNode = lo;
    hi = NNODES;
    while (lo < hi) { int mid = (lo + hi) >> 1; if (basep[mid] >= tg2) hi = mid; else lo = mid + 1; }
    const int endNode = lo;

    const int s0 = basep[firstNode];
    const int nslots = basep[endNode] - s0;
    const int ntiles = (nslots + 63) >> 6;

    // stage slot metadata
    const int ntot = ntiles << 6;
    for (int j = t; j < ntot; j += 256) {
        bool v = j < nslots;
        seid[j] = v ? sorted[s0 + j] : 0;
        ssr[j] = v ? (unsigned short)ssrc_g[s0 + j] : 0;
    }
    // snode fill by node; collect zero-degree nodes
    for (int n = firstNode + t; n < endNode; n += 256) {
        int b0 = basep[n], b1 = basep[n + 1];
        if (b0 == b1) { int i = atomicAdd(&zcnt, 1); if (i < 32) zlist[i] = n; }
        for (int j = b0 - s0; j < b1 - s0; ++j) snode[j] = (unsigned short)n;
    }
    // stage W3 (persistent)
#pragma unroll
    for (int j = 0; j < 8; ++j) {
        int idx = t + 256 * j;
        int n = idx >> 4, q = idx & 15;
        uint4 wv = *(const uint4*)(W3t + n * 128 + q * 8);
        *(uint4*)((char*)Bs + n * 256 + ((q * 16) ^ ((n & 7) << 4))) = wv;
    }
    __syncthreads();

    const int q5 = t & 31, r5 = t >> 5;
    float4 rE[8];
    uint2 rP[8];
    auto loadT = [&](int ti) {
#pragma unroll
        for (int j = 0; j < 8; ++j) {
            int sl = (ti << 6) + r5 + 8 * j;
            int eid = seid[sl];
            rE[j] = ((const float4*)e)[(size_t)eid * 32 + q5];
            int es = ssr[sl];
            rP[j] = *(const uint2*)(P1 + (size_t)es * 128 + q5 * 4);
        }
    };
    auto storeT = [&]() {
#pragma unroll
        for (int j = 0; j < 8; ++j) {
            int r = r5 + 8 * j;
            uint2 pv;
            pv.x = f2bf(rE[j].x) | (f2bf(rE[j].y) << 16);
            pv.y = f2bf(rE[j].z) | (f2bf(rE[j].w) << 16);
            unsigned off = (unsigned)(r * 256) + (((unsigned)(q5 * 8)) ^ (((unsigned)(r & 7)) << 4));
            *(uint2*)((char*)As + off) = pv;
            *(uint2*)((char*)P1s + off) = rP[j];
        }
    };
    if (ntiles > 0) loadT(0);

    const int w = t >> 6, lane = t & 63, lrow = lane & 15, lkb = lane >> 4;
    float bpf[8];
#pragma unroll
    for (int nt = 0; nt < 8; ++nt) bpf[nt] = bpre[nt * 16 + lrow];

    // per-column running segment state (threads t<128)
    const int col = t & 127;
    float ss = 0.f, qq = 0.f, mx = -3.4e38f, mn = 3.4e38f;
    int cur = -1;
    auto flushN = [&]() {
        float dg = (float)(basep[cur + 1] - basep[cur]);
        float mean_g = ss / dg;
        float var = fmaxf(qq / dg - mean_g * mean_g, 0.f);
        float sd = sqrtf(var + EPSF);
        float c2 = bf2f(P2[(size_t)cur * 128 + col]);
        unsigned short* row = Abuf + (size_t)cur * 640 + 128 + col;
        row[0] = (unsigned short)f2bf(mean_g + c2);
        row[128] = (unsigned short)f2bf(mx + c2);
        row[256] = (unsigned short)f2bf(mn + c2);
        row[384] = (unsigned short)f2bf(sd);
    };

    for (int ti = 0; ti < ntiles; ++ti) {
        storeT();                       // As,P1s <- tile ti
        __syncthreads();
        if (ti + 1 < ntiles) loadT(ti + 1);  // prefetch next tile (hidden under MFMA+scan)
        f32x4 acc[8];
#pragma unroll
        for (int i = 0; i < 8; ++i) acc[i] = (f32x4){0.f, 0.f, 0.f, 0.f};
        const char* Ab = (const char*)As + (w * 16 + lrow) * 256;
        const unsigned aswz = (unsigned)(((w * 16 + lrow) & 7) << 4);
#pragma unroll
        for (int kk = 0; kk < 4; ++kk) {
            int kbyte = (kk * 32 + lkb * 8) * 2;
            short8 af = *(const short8*)(Ab + (kbyte ^ aswz));
#pragma unroll
            for (int nt = 0; nt < 8; ++nt) {
                int n = nt * 16 + lrow;
                short8 bf = *(const short8*)((const char*)Bs + n * 256 + (kbyte ^ ((n & 7) << 4)));
                acc[nt] = __builtin_amdgcn_mfma_f32_16x16x32_bf16(af, bf, acc[nt], 0, 0, 0);
            }
        }
        __syncthreads();                // MFMA reads of As done
        // scatter g = acc + bpre + P1s back into As
#pragma unroll
        for (int nt = 0; nt < 8; ++nt) {
            int cc = nt * 16 + lrow;
#pragma unroll
            for (int i = 0; i < 4; ++i) {
                int lr = w * 16 + lkb * 4 + i;
                unsigned off = (unsigned)(lr * 256) + (((unsigned)(cc * 2)) ^ (((unsigned)(lr & 7)) << 4));
                float p1v = bf2f(*(const unsigned short*)((const char*)P1s + off));
                *(unsigned short*)((char*)As + off) = (unsigned short)f2bf(acc[nt][i] + bpf[nt] + p1v);
            }
        }
        __syncthreads();                // scatter visible
        // segmented column scan
        const int rows = min(64, nslots - (ti << 6));
        if (t < 128) {
            for (int r = 0; r < rows; ++r) {
                int n = (int)snode[(ti << 6) + r];
                if (n != cur) {
                    if (cur >= 0) flushN();
                    cur = n; ss = 0.f; qq = 0.f; mx = -3.4e38f; mn = 3.4e38f;
                }
                unsigned off = (unsigned)(r * 256) + (((unsigned)(col * 2)) ^ (((unsigned)(r & 7)) << 4));
                float x = bf2f(*(const unsigned short*)((const char*)As + off));
                ss += x; qq = fmaf(x, x, qq);
                mx = fmaxf(mx, x); mn = fminf(mn, x);
            }
        }
        __syncthreads();                // scan reads of As done before next storeT
    }
    if (t < 128 && cur >= 0) flushN();
    if (t < 128) {
        int zc = min(zcnt, 32);
        for (int i = 0; i < zc; ++i) {
            int n = zlist[i];
            unsigned short* row = Abuf + (size_t)n * 640 + 128 + col;
            row[0] = 0; row[128] = 0; row[256] = 0; row[384] = 0;
        }
    }
}

// ---------------- out = C0 + amp*C1 + att*C2 + b, *snorm ; C = A[50000,640] @ Bhat[640,384] ----------------
__global__ __launch_bounds__(512) void k_gemm_post(const unsigned short* __restrict__ Abuf,
                                                   const unsigned short* __restrict__ Bhat,
                                                   const float* __restrict__ bpost,
                                                   const float* __restrict__ snorm,
                                                   const int* __restrict__ basep,
                                                   float* __restrict__ out) {
    __shared__ __align__(16) unsigned short As[2][128 * 32];
    __shared__ __align__(16) unsigned short Bs[2][384 * 32];
    __shared__ float sAmp[128], sAtt[128], sSn[128], sBp[128];
    const int t = threadIdx.x;
    const size_t row0 = (size_t)blockIdx.x * 128;
    if (t < 128) {
        size_t nn = row0 + t;
        float a = 0.f, b = 0.f, sn = 0.f;
        if (nn < NNODES) {
            int dgi = basep[nn + 1] - basep[nn];
            a = logf((float)dgi + 1.f) * (1.f / AVGDLOG);
            b = AVGDLOG / logf(fmaxf((float)dgi, 1.f) + 1.f);
            sn = snorm[nn];
        }
        sAmp[t] = a; sAtt[t] = b; sSn[t] = sn; sBp[t] = bpost[t];
    }
    const int arow = t >> 2, ak4 = t & 3;
    auto loadA = [&](int kc, uint4& ra) {
        ra = (uint4){0u, 0u, 0u, 0u};
        if (row0 + arow < NNODES)
            ra = *(const uint4*)(Abuf + (row0 + arow) * 640 + kc * 32 + ak4 * 8);
    };
    auto loadB = [&](int kc, uint4* rb) {
#pragma unroll
        for (int j = 0; j < 3; ++j) {
            int idx = t + 512 * j;
            int n = idx >> 2, k4 = idx & 3;
            rb[j] = *(const uint4*)(Bhat + ((size_t)kc * 384 + n) * 32 + k4 * 8);
        }
    };
    auto storeLDS = [&](int buf, const uint4& ra, const uint4* rb) {
        *(uint4*)((char*)As[buf] + arow * 64 + ((ak4 * 16) ^ (((arow >> 1) & 3) << 4))) = ra;
#pragma unroll
        for (int j = 0; j < 3; ++j) {
            int idx = t + 512 * j;
            int n = idx >> 2, k4 = idx & 3;
            *(uint4*)((char*)Bs[buf] + n * 64 + ((k4 * 16) ^ (((n >> 1) & 3) << 4))) = rb[j];
        }
    };
    const int w = t >> 6, wm = w & 1, wn = w >> 1;
    const int lane = t & 63, lrow = lane & 15, lkb = lane >> 4;
    f32x4 acc[4][6];
#pragma unroll
    for (int a = 0; a < 4; ++a)
#pragma unroll
        for (int b = 0; b < 6; ++b) acc[a][b] = (f32x4){0.f, 0.f, 0.f, 0.f};

    uint4 ra, rb[3];
    loadA(0, ra); loadB(0, rb);
    storeLDS(0, ra, rb);
    int cur = 0;
    for (int kc = 0; kc < 20; ++kc) {
        if (kc < 19) { loadA(kc + 1, ra); loadB(kc + 1, rb); }
        __syncthreads();
        short8 af[4];
#pragma unroll
        for (int mi = 0; mi < 4; ++mi) {
            int r = wm * 64 + mi * 16 + lrow;
            af[mi] = *(const short8*)((const char*)As[cur] + r * 64 + ((lkb * 16) ^ (((r >> 1) & 3) << 4)));
        }
        short8 bfv[6];
#pragma unroll
        for (int g = 0; g < 3; ++g)
#pragma unroll
            for (int j = 0; j < 2; ++j) {
                int nn = g * 128 + wn * 32 + j * 16 + lrow;
                bfv[g * 2 + j] = *(const short8*)((const char*)Bs[cur] + nn * 64 + ((lkb * 16) ^ (((nn >> 1) & 3) << 4)));
            }
#pragma unroll
        for (int mi = 0; mi < 4; ++mi)
#pragma unroll
            for (int f = 0; f < 6; ++f)
                acc[mi][f] = __builtin_amdgcn_mfma_f32_16x16x32_bf16(af[mi], bfv[f], acc[mi][f], 0, 0, 0);
        if (kc < 19) storeLDS(cur ^ 1, ra, rb);
        cur ^= 1;
    }
#pragma unroll
    for (int mi = 0; mi < 4; ++mi)
#pragma unroll
        for (int j = 0; j < 2; ++j)
#pragma unroll
            for (int i = 0; i < 4; ++i) {
                int r = wm * 64 + mi * 16 + lkb * 4 + i;
                size_t grow = row0 + r;
                if (grow < NNODES) {
                    int c = wn * 32 + j * 16 + lrow;
                    float v = acc[mi][j][i] + sAmp[r] * acc[mi][2 + j][i] + sAtt[r] * acc[mi][4 + j][i] + sBp[c];
                    out[grow * 128 + c] = v * sSn[r];
                }
            }
}

extern "C" void kernel_launch(void* const* d_in, const int* in_sizes, int n_in,
                              void* d_out, int out_size, void* d_ws, size_t ws_size,
                              hipStream_t stream) {
    const float* h = (const float*)d_in[0];
    const float* e = (const float*)d_in[1];
    const float* snorm = (const float*)d_in[2];
    const int* src = (const int*)d_in[3];
    const int* dst = (const int*)d_in[4];
    const float* Wpre = (const float*)d_in[5];
    const float* bpre = (const float*)d_in[6];
    const float* Wpost = (const float*)d_in[7];
    const float* bpost = (const float*)d_in[8];
    float* out = (float*)d_out;

    char* p = (char*)d_ws;
    auto alloc = [&](size_t bytes) { char* r = p; p += (bytes + 255) & ~(size_t)255; return r; };
    unsigned short* P1 = (unsigned short*)alloc((size_t)NNODES * 128 * 2);
    unsigned short* P2 = (unsigned short*)alloc((size_t)NNODES * 128 * 2);
    unsigned short* Abuf = (unsigned short*)alloc((size_t)NNODES * 640 * 2);
    unsigned short* W3t = (unsigned short*)alloc(128 * 128 * 2);
    unsigned short* W12t = (unsigned short*)alloc(256 * 128 * 2);
    unsigned short* Bhat = (unsigned short*)alloc((size_t)640 * 384 * 2);
    unsigned* deg = (unsigned*)alloc((size_t)NNODES * 4);
    int* basep = (int*)alloc((size_t)(NNODES + 1) * 4);
    int* cursor = (int*)alloc((size_t)NNODES * 4);
    int* sorted = (int*)alloc((size_t)NEDGES * 4);
    int* ssrc = (int*)alloc((size_t)NEDGES * 4);

    k_zero<<<(NNODES + 255) / 256, 256, 0, stream>>>(deg);
    k_count<<<(NEDGES + 255) / 256, 256, 0, stream>>>(dst, deg);
    k_scan<<<1, 1024, 0, stream>>>(deg, basep, cursor);
    k_scatter<<<(NEDGES + 255) / 256, 256, 0, stream>>>(dst, src, cursor, sorted, ssrc);
    k_convW<<<(640 * 384 + 255) / 256, 256, 0, stream>>>(Wpre, Wpost, W3t, W12t, Bhat);
    k_p12<<<(NNODES + 63) / 64, 256, 0, stream>>>(h, W12t, P1, P2, Abuf);
    k_fused<<<NCHUNK, 256, 0, stream>>>(e, sorted, ssrc, basep, W3t, bpre, P1, P2, Abuf);
    k_gemm_post<<<(NNODES + 127) / 128, 512, 0, stream>>>(Abuf, Bhat, bpost, snorm, basep, out);
}

// Round 7
// 539.623 us; speedup vs baseline: 1.0685x; 1.0685x over previous
//
#include <hip/hip_runtime.h>
#include <math.h>

#define NNODES 50000
#define NEDGES 800000
#define AVGDLOG 2.833f
#define EPSF 1e-5f
#define TPB_E 16

typedef __attribute__((ext_vector_type(8))) short short8;
typedef __attribute__((ext_vector_type(4))) float f32x4;

__device__ __forceinline__ unsigned f2bf(float x) {
    unsigned u = __float_as_uint(x);
    return (u + 0x7FFFu + ((u >> 16) & 1u)) >> 16;
}
__device__ __forceinline__ float bf2f(unsigned lo16) {
    return __uint_as_float(lo16 << 16);
}
__device__ __forceinline__ void up8(uint4 v, float* f) {
    f[0] = bf2f(v.x & 0xffffu); f[1] = bf2f(v.x >> 16);
    f[2] = bf2f(v.y & 0xffffu); f[3] = bf2f(v.y >> 16);
    f[4] = bf2f(v.z & 0xffffu); f[5] = bf2f(v.z >> 16);
    f[6] = bf2f(v.w & 0xffffu); f[7] = bf2f(v.w >> 16);
}
__device__ __forceinline__ uint4 pk8(const float* f) {
    uint4 v;
    v.x = f2bf(f[0]) | (f2bf(f[1]) << 16);
    v.y = f2bf(f[2]) | (f2bf(f[3]) << 16);
    v.z = f2bf(f[4]) | (f2bf(f[5]) << 16);
    v.w = f2bf(f[6]) | (f2bf(f[7]) << 16);
    return v;
}

// ---------------- CSR ----------------
__global__ void k_zero(unsigned* __restrict__ deg) {
    int i = blockIdx.x * 256 + threadIdx.x;
    if (i < NNODES) deg[i] = 0u;
}
__global__ void k_count(const int* __restrict__ dst, unsigned* __restrict__ deg) {
    int i = blockIdx.x * 256 + threadIdx.x;
    if (i < NEDGES) atomicAdd(&deg[dst[i]], 1u);
}
__global__ __launch_bounds__(1024) void k_scan(const unsigned* __restrict__ deg,
                                               int* __restrict__ base, int* __restrict__ cursor) {
    __shared__ int ps[1024];
    const int t = threadIdx.x;
    const int lo = t * 52;
    int s = 0;
    if (lo + 52 <= NNODES) {
        const int4* dp = (const int4*)(deg + lo);
#pragma unroll
        for (int i = 0; i < 13; ++i) { int4 v = dp[i]; s += v.x + v.y + v.z + v.w; }
    } else {
        for (int i = lo; i < NNODES; ++i) s += (int)deg[i];
    }
    ps[t] = s;
    __syncthreads();
    for (int off = 1; off < 1024; off <<= 1) {
        int v = (t >= off) ? ps[t - off] : 0;
        __syncthreads();
        ps[t] += v;
        __syncthreads();
    }
    int run = (t > 0) ? ps[t - 1] : 0;
    if (lo + 52 <= NNODES) {
        const int4* dp = (const int4*)(deg + lo);
        int4* bp = (int4*)(base + lo);
        int4* cp = (int4*)(cursor + lo);
#pragma unroll
        for (int i = 0; i < 13; ++i) {
            int4 v = dp[i]; int4 b;
            b.x = run; run += v.x; b.y = run; run += v.y;
            b.z = run; run += v.z; b.w = run; run += v.w;
            bp[i] = b; cp[i] = b;
        }
    } else {
        for (int i = lo; i < NNODES; ++i) { base[i] = run; cursor[i] = run; run += (int)deg[i]; }
    }
    if (t == 1023) base[NNODES] = run;
}
__global__ void k_scatter(const int* __restrict__ dst, const int* __restrict__ src,
                          int* __restrict__ cursor, int* __restrict__ sorted,
                          int* __restrict__ ssrc) {
    int i = blockIdx.x * 256 + threadIdx.x;
    if (i < NEDGES) {
        int d = dst[i];
        int slot = atomicAdd(&cursor[d], 1);
        sorted[slot] = i;
        ssrc[slot] = src[i];
    }
}

// ---------------- weight prep ----------------
__global__ void k_convW(const float* __restrict__ Wpre, const float* __restrict__ Wpost,
                        unsigned short* __restrict__ W3t, unsigned short* __restrict__ W12t,
                        unsigned short* __restrict__ Bhat) {
    int i = blockIdx.x * 256 + threadIdx.x;
    if (i < 128 * 128) {
        int n = i & 127, k = i >> 7;
        W3t[n * 128 + k] = (unsigned short)f2bf(Wpre[(256 + k) * 128 + n]);
    }
    if (i < 256 * 128) {
        int n = i >> 7, k = i & 127;
        float v = (n < 128) ? Wpre[k * 128 + n] : Wpre[(128 + k) * 128 + (n - 128)];
        W12t[n * 128 + k] = (unsigned short)f2bf(v);
    }
    if (i < 640 * 384) {
        int kc = i / (384 * 32);
        int rem = i % (384 * 32);
        int n = rem >> 5, kk = rem & 31;
        int k = kc * 32 + kk, c = n & 127, g = n >> 7;
        float v;
        if (g == 0) v = Wpost[k * 128 + c];
        else if (g == 1) v = (k < 128) ? 0.f : Wpost[(512 + k) * 128 + c];
        else v = (k < 128) ? 0.f : Wpost[(1024 + k) * 128 + c];
        Bhat[i] = (unsigned short)f2bf(v);
    }
}

// ---------------- P12 = h @ [W1|W2] (MFMA); also emits bf16(h) into Abuf[:,0:128] ----------------
__global__ __launch_bounds__(256) void k_p12(const float* __restrict__ h,
                                             const unsigned short* __restrict__ W12t,
                                             unsigned short* __restrict__ P1,
                                             unsigned short* __restrict__ P2,
                                             unsigned short* __restrict__ Abuf) {
    __shared__ __align__(16) unsigned short As[64 * 128];
    __shared__ __align__(16) unsigned short Bs[256 * 128];
    const int t = threadIdx.x;
    const size_t row0 = (size_t)blockIdx.x * 64;
#pragma unroll
    for (int j = 0; j < 16; ++j) {
        int idx = t + 256 * j;
        int n = idx >> 4, q = idx & 15;
        uint4 wv = *(const uint4*)(W12t + n * 128 + q * 8);
        *(uint4*)((char*)Bs + n * 256 + ((q * 16) ^ ((n & 7) << 4))) = wv;
    }
#pragma unroll
    for (int j = 0; j < 8; ++j) {
        int idx = t + 256 * j;
        int r = idx >> 5, q = idx & 31;
        size_t row = row0 + r;
        uint2 p = {0u, 0u};
        if (row < NNODES) {
            float4 z = ((const float4*)h)[row * 32 + q];
            p.x = f2bf(z.x) | (f2bf(z.y) << 16);
            p.y = f2bf(z.z) | (f2bf(z.w) << 16);
            *(uint2*)(Abuf + row * 640 + q * 4) = p;
        }
        *(uint2*)((char*)As + r * 256 + ((q * 8) ^ ((r & 7) << 4))) = p;
    }
    __syncthreads();
    const int w = t >> 6, lane = t & 63, lrow = lane & 15, lkb = lane >> 4;
    f32x4 acc[16];
#pragma unroll
    for (int i = 0; i < 16; ++i) acc[i] = (f32x4){0.f, 0.f, 0.f, 0.f};
    const char* Abase = (const char*)As + (w * 16 + lrow) * 256;
    const unsigned aswz = (unsigned)(((w * 16 + lrow) & 7) << 4);
#pragma unroll
    for (int kk = 0; kk < 4; ++kk) {
        int kbyte = (kk * 32 + lkb * 8) * 2;
        short8 af = *(const short8*)(Abase + (kbyte ^ aswz));
#pragma unroll
        for (int nt = 0; nt < 16; ++nt) {
            int n = nt * 16 + lrow;
            short8 bf = *(const short8*)((const char*)Bs + n * 256 + (kbyte ^ ((n & 7) << 4)));
            acc[nt] = __builtin_amdgcn_mfma_f32_16x16x32_bf16(af, bf, acc[nt], 0, 0, 0);
        }
    }
#pragma unroll
    for (int half = 0; half < 2; ++half) {
        __syncthreads();
#pragma unroll
        for (int nt = 0; nt < 8; ++nt) {
            int c = nt * 16 + lrow;
#pragma unroll
            for (int i = 0; i < 4; ++i) {
                int lr = w * 16 + lkb * 4 + i;
                *(unsigned short*)((char*)As + lr * 256 + ((c * 2) ^ ((lr & 7) << 4))) =
                    (unsigned short)f2bf(acc[half * 8 + nt][i]);
            }
        }
        __syncthreads();
        unsigned short* dstP = half ? P2 : P1;
#pragma unroll
        for (int j = 0; j < 4; ++j) {
            int idx = t + 256 * j;
            int r = idx >> 4, q = idx & 15;
            size_t row = row0 + r;
            if (row < NNODES) {
                uint4 v = *(const uint4*)((const char*)As + r * 256 + ((q * 16) ^ ((r & 7) << 4)));
                *(uint4*)(dstP + row * 128 + q * 8) = v;
            }
        }
    }
}

// ---------------- G[sorted slot] = bf16(e[eid] @ W3 + bpre) (MFMA, pipelined multi-tile) ----------------
__global__ __launch_bounds__(256) void k_gemm_e(const float* __restrict__ e,
                                                const int* __restrict__ sorted,
                                                const unsigned short* __restrict__ W3t,
                                                const float* __restrict__ bpre,
                                                unsigned short* __restrict__ G) {
    __shared__ __align__(16) unsigned short Bs[128 * 128];   // persistent W3
    __shared__ __align__(16) unsigned short As[2][64 * 128]; // double-buffered A
    __shared__ int Seid[TPB_E * 64];
    const int t = threadIdx.x;
    const int tile0 = blockIdx.x * TPB_E;
    const int ntiles = min(TPB_E, 12500 - tile0);

    for (int j = t; j < TPB_E * 64; j += 256) {
        int slot = tile0 * 64 + j;
        Seid[j] = (slot < NEDGES) ? sorted[slot] : 0;
    }
    __syncthreads();

    const int q = t & 31, r5 = t >> 5;
    auto loadE = [&](int ti, float4* ra) {
#pragma unroll
        for (int j = 0; j < 8; ++j) {
            int r = r5 + 8 * j;
            int eid = Seid[ti * 64 + r];
            ra[j] = ((const float4*)e)[(size_t)eid * 32 + q];
        }
    };
    auto storeA = [&](int buf, const float4* ra) {
#pragma unroll
        for (int j = 0; j < 8; ++j) {
            int r = r5 + 8 * j;
            uint2 pv;
            pv.x = f2bf(ra[j].x) | (f2bf(ra[j].y) << 16);
            pv.y = f2bf(ra[j].z) | (f2bf(ra[j].w) << 16);
            *(uint2*)((char*)As[buf] + r * 256 + ((q * 8) ^ ((r & 7) << 4))) = pv;
        }
    };

    float4 ra[8];
    loadE(0, ra);
#pragma unroll
    for (int j = 0; j < 8; ++j) {
        int idx = t + 256 * j;
        int n = idx >> 4, qq = idx & 15;
        uint4 wv = *(const uint4*)(W3t + n * 128 + qq * 8);
        *(uint4*)((char*)Bs + n * 256 + ((qq * 16) ^ ((n & 7) << 4))) = wv;
    }
    storeA(0, ra);
    if (ntiles > 1) loadE(1, ra);
    __syncthreads();

    const int w = t >> 6, lane = t & 63, lrow = lane & 15, lkb = lane >> 4;
    float bpf[8];
#pragma unroll
    for (int nt = 0; nt < 8; ++nt) bpf[nt] = bpre[nt * 16 + lrow];

    for (int ti = 0; ti < ntiles; ++ti) {
        const int c = ti & 1;
        f32x4 acc[8];
#pragma unroll
        for (int i = 0; i < 8; ++i) acc[i] = (f32x4){0.f, 0.f, 0.f, 0.f};
        const char* Ab = (const char*)As[c] + (w * 16 + lrow) * 256;
        const unsigned aswz = (unsigned)(((w * 16 + lrow) & 7) << 4);
#pragma unroll
        for (int kk = 0; kk < 4; ++kk) {
            int kbyte = (kk * 32 + lkb * 8) * 2;
            short8 af = *(const short8*)(Ab + (kbyte ^ aswz));
#pragma unroll
            for (int nt = 0; nt < 8; ++nt) {
                int n = nt * 16 + lrow;
                short8 bf = *(const short8*)((const char*)Bs + n * 256 + (kbyte ^ ((n & 7) << 4)));
                acc[nt] = __builtin_amdgcn_mfma_f32_16x16x32_bf16(af, bf, acc[nt], 0, 0, 0);
            }
        }
        __syncthreads();  // MFMA reads of As[c] + prev flush reads drained
#pragma unroll
        for (int nt = 0; nt < 8; ++nt) {
            int cc = nt * 16 + lrow;
#pragma unroll
            for (int i = 0; i < 4; ++i) {
                int lr = w * 16 + lkb * 4 + i;
                *(unsigned short*)((char*)As[c] + lr * 256 + ((cc * 2) ^ ((lr & 7) << 4))) =
                    (unsigned short)f2bf(acc[nt][i] + bpf[nt]);
            }
        }
        if (ti + 1 < ntiles) {
            storeA(c ^ 1, ra);
            if (ti + 2 < ntiles) loadE(ti + 2, ra);
        }
        __syncthreads();  // scatter + next-tile stage visible
        const size_t row0 = (size_t)(tile0 + ti) * 64;
#pragma unroll
        for (int j = 0; j < 4; ++j) {
            int idx = t + 256 * j;
            int r = idx >> 4, qq = idx & 15;
            uint4 v = *(const uint4*)((const char*)As[c] + r * 256 + ((qq * 16) ^ ((r & 7) << 4)));
            *(uint4*)(G + (row0 + r) * 128 + qq * 8) = v;
        }
    }
}

// ---------------- segmented reduce: m = G[slot] + P1[ssrc[slot]] + P2[n]; stats -> Abuf[:,128:640] ----------------
__global__ __launch_bounds__(256) void k_reduce(const unsigned short* __restrict__ G,
                                                const unsigned short* __restrict__ P1,
                                                const unsigned short* __restrict__ P2,
                                                const int* __restrict__ basep,
                                                const int* __restrict__ ssrc,
                                                unsigned short* __restrict__ Abuf) {
    const int t = threadIdx.x;
    const int n = blockIdx.x * 4 + (t >> 6);
    const int lane = t & 63, lq = lane >> 4, lc = lane & 15;
    int b0 = basep[n], b1 = basep[n + 1];
    int dg = b1 - b0;
    float s[8], q2[8], mx[8], mn[8];
#pragma unroll
    for (int j = 0; j < 8; ++j) { s[j] = 0.f; q2[j] = 0.f; mx[j] = -3.4e38f; mn[j] = 3.4e38f; }
    if (dg > 0) {
        float p2f[8];
        up8(*(const uint4*)(P2 + (size_t)n * 128 + lc * 8), p2f);
        for (int sl = b0 + lq; sl < b1; sl += 4) {
            int es = ssrc[sl];
            float gf[8], p1f[8];
            up8(*(const uint4*)(G + (size_t)sl * 128 + lc * 8), gf);
            up8(*(const uint4*)(P1 + (size_t)es * 128 + lc * 8), p1f);
#pragma unroll
            for (int j = 0; j < 8; ++j) {
                float m = gf[j] + p1f[j] + p2f[j];
                s[j] += m; q2[j] += m * m;
                mx[j] = fmaxf(mx[j], m); mn[j] = fminf(mn[j], m);
            }
        }
    }
#pragma unroll
    for (int off = 16; off <= 32; off <<= 1) {
#pragma unroll
        for (int j = 0; j < 8; ++j) {
            s[j] += __shfl_xor(s[j], off);
            q2[j] += __shfl_xor(q2[j], off);
            mx[j] = fmaxf(mx[j], __shfl_xor(mx[j], off));
            mn[j] = fminf(mn[j], __shfl_xor(mn[j], off));
        }
    }
    if (lane < 16) {
        float mean[8], sd[8], X[8], N[8];
        if (dg > 0) {
            float ds = (float)dg;
#pragma unroll
            for (int j = 0; j < 8; ++j) {
                mean[j] = s[j] / ds;
                float v = fmaxf(q2[j] / ds - mean[j] * mean[j], 0.f);
                sd[j] = sqrtf(v + EPSF);
                X[j] = mx[j]; N[j] = mn[j];
            }
        } else {
#pragma unroll
            for (int j = 0; j < 8; ++j) { mean[j] = 0.f; sd[j] = 0.f; X[j] = 0.f; N[j] = 0.f; }
        }
        unsigned short* row = Abuf + (size_t)n * 640 + 128 + lc * 8;
        *(uint4*)(row) = pk8(mean);
        *(uint4*)(row + 128) = pk8(X);
        *(uint4*)(row + 256) = pk8(N);
        *(uint4*)(row + 384) = pk8(sd);
    }
}

// ---------------- out = C0 + amp*C1 + att*C2 + b, *snorm ; C = A[50000,640] @ Bhat[640,384] ----------------
// 64-row tiles, 256 threads, grid 782: each wave owns 32 out-cols across all 3 diag groups.
__global__ __launch_bounds__(256) void k_gemm_post(const unsigned short* __restrict__ Abuf,
                                                   const unsigned short* __restrict__ Bhat,
                                                   const float* __restrict__ bpost,
                                                   const float* __restrict__ snorm,
                                                   const int* __restrict__ basep,
                                                   float* __restrict__ out) {
    __shared__ __align__(16) unsigned short As[2][64 * 32];
    __shared__ __align__(16) unsigned short Bs[2][384 * 32];
    __shared__ float sAmp[64], sAtt[64], sSn[64], sBp[128];
    const int t = threadIdx.x;
    const size_t row0 = (size_t)blockIdx.x * 64;
    if (t < 64) {
        size_t nn = row0 + t;
        float a = 0.f, b = 0.f, sn = 0.f;
        if (nn < NNODES) {
            int dgi = basep[nn + 1] - basep[nn];
            a = logf((float)dgi + 1.f) * (1.f / AVGDLOG);
            b = AVGDLOG / logf(fmaxf((float)dgi, 1.f) + 1.f);
            sn = snorm[nn];
        }
        sAmp[t] = a; sAtt[t] = b; sSn[t] = sn;
    }
    if (t < 128) sBp[t] = bpost[t];
    const int arow = t >> 2, ak4 = t & 3;
    auto loadA = [&](int kc, uint4& ra) {
        ra = (uint4){0u, 0u, 0u, 0u};
        if (row0 + arow < NNODES)
            ra = *(const uint4*)(Abuf + (row0 + arow) * 640 + kc * 32 + ak4 * 8);
    };
    auto loadB = [&](int kc, uint4* rb) {
#pragma unroll
        for (int j = 0; j < 6; ++j) {
            int idx = t + 256 * j;
            int n = idx >> 2, k4 = idx & 3;
            rb[j] = *(const uint4*)(Bhat + ((size_t)kc * 384 + n) * 32 + k4 * 8);
        }
    };
    auto storeLDS = [&](int buf, const uint4& ra, const uint4* rb) {
        *(uint4*)((char*)As[buf] + arow * 64 + ((ak4 * 16) ^ (((arow >> 1) & 3) << 4))) = ra;
#pragma unroll
        for (int j = 0; j < 6; ++j) {
            int idx = t + 256 * j;
            int n = idx >> 2, k4 = idx & 3;
            *(uint4*)((char*)Bs[buf] + n * 64 + ((k4 * 16) ^ (((n >> 1) & 3) << 4))) = rb[j];
        }
    };
    const int w = t >> 6;
    const int lane = t & 63, lrow = lane & 15, lkb = lane >> 4;
    f32x4 acc[4][6];
#pragma unroll
    for (int a = 0; a < 4; ++a)
#pragma unroll
        for (int b = 0; b < 6; ++b) acc[a][b] = (f32x4){0.f, 0.f, 0.f, 0.f};

    uint4 ra, rb[6];
    loadA(0, ra); loadB(0, rb);
    storeLDS(0, ra, rb);
    int cur = 0;
    for (int kc = 0; kc < 20; ++kc) {
        if (kc < 19) { loadA(kc + 1, ra); loadB(kc + 1, rb); }
        __syncthreads();
        short8 af[4];
#pragma unroll
        for (int mi = 0; mi < 4; ++mi) {
            int r = mi * 16 + lrow;
            af[mi] = *(const short8*)((const char*)As[cur] + r * 64 + ((lkb * 16) ^ (((r >> 1) & 3) << 4)));
        }
        short8 bfv[6];
#pragma unroll
        for (int g = 0; g < 3; ++g)
#pragma unroll
            for (int j = 0; j < 2; ++j) {
                int nn = g * 128 + w * 32 + j * 16 + lrow;
                bfv[g * 2 + j] = *(const short8*)((const char*)Bs[cur] + nn * 64 + ((lkb * 16) ^ (((nn >> 1) & 3) << 4)));
            }
#pragma unroll
        for (int mi = 0; mi < 4; ++mi)
#pragma unroll
            for (int f = 0; f < 6; ++f)
                acc[mi][f] = __builtin_amdgcn_mfma_f32_16x16x32_bf16(af[mi], bfv[f], acc[mi][f], 0, 0, 0);
        if (kc < 19) storeLDS(cur ^ 1, ra, rb);
        cur ^= 1;
    }
#pragma unroll
    for (int mi = 0; mi < 4; ++mi)
#pragma unroll
        for (int j = 0; j < 2; ++j)
#pragma unroll
            for (int i = 0; i < 4; ++i) {
                int r = mi * 16 + lkb * 4 + i;
                size_t grow = row0 + r;
                if (grow < NNODES) {
                    int c = w * 32 + j * 16 + lrow;
                    float v = acc[mi][j][i] + sAmp[r] * acc[mi][2 + j][i] + sAtt[r] * acc[mi][4 + j][i] + sBp[c];
                    out[grow * 128 + c] = v * sSn[r];
                }
            }
}

extern "C" void kernel_launch(void* const* d_in, const int* in_sizes, int n_in,
                              void* d_out, int out_size, void* d_ws, size_t ws_size,
                              hipStream_t stream) {
    const float* h = (const float*)d_in[0];
    const float* e = (const float*)d_in[1];
    const float* snorm = (const float*)d_in[2];
    const int* src = (const int*)d_in[3];
    const int* dst = (const int*)d_in[4];
    const float* Wpre = (const float*)d_in[5];
    const float* bpre = (const float*)d_in[6];
    const float* Wpost = (const float*)d_in[7];
    const float* bpost = (const float*)d_in[8];
    float* out = (float*)d_out;

    char* p = (char*)d_ws;
    auto alloc = [&](size_t bytes) { char* r = p; p += (bytes + 255) & ~(size_t)255; return r; };
    unsigned short* P1 = (unsigned short*)alloc((size_t)NNODES * 128 * 2);
    unsigned short* P2 = (unsigned short*)alloc((size_t)NNODES * 128 * 2);
    unsigned short* Abuf = (unsigned short*)alloc((size_t)NNODES * 640 * 2);
    unsigned short* G = (unsigned short*)alloc((size_t)NEDGES * 128 * 2);
    unsigned short* W3t = (unsigned short*)alloc(128 * 128 * 2);
    unsigned short* W12t = (unsigned short*)alloc(256 * 128 * 2);
    unsigned short* Bhat = (unsigned short*)alloc((size_t)640 * 384 * 2);
    unsigned* deg = (unsigned*)alloc((size_t)NNODES * 4);
    int* basep = (int*)alloc((size_t)(NNODES + 1) * 4);
    int* cursor = (int*)alloc((size_t)NNODES * 4);
    int* sorted = (int*)alloc((size_t)NEDGES * 4);
    int* ssrc = (int*)alloc((size_t)NEDGES * 4);

    k_zero<<<(NNODES + 255) / 256, 256, 0, stream>>>(deg);
    k_count<<<(NEDGES + 255) / 256, 256, 0, stream>>>(dst, deg);
    k_scan<<<1, 1024, 0, stream>>>(deg, basep, cursor);
    k_scatter<<<(NEDGES + 255) / 256, 256, 0, stream>>>(dst, src, cursor, sorted, ssrc);
    k_convW<<<(640 * 384 + 255) / 256, 256, 0, stream>>>(Wpre, Wpost, W3t, W12t, Bhat);
    k_p12<<<(NNODES + 63) / 64, 256, 0, stream>>>(h, W12t, P1, P2, Abuf);
    k_gemm_e<<<(12500 + TPB_E - 1) / TPB_E, 256, 0, stream>>>(e, sorted, W3t, bpre, G);
    k_reduce<<<NNODES / 4, 256, 0, stream>>>(G, P1, P2, basep, ssrc, Abuf);
    k_gemm_post<<<(NNODES + 63) / 64, 256, 0, stream>>>(Abuf, Bhat, bpost, snorm, basep, out);
}